// Round 7
// baseline (186.469 us; speedup 1.0000x reference)
//
#include <hip/hip_runtime.h>
#include <math.h>

#define BB 2
#define TT 2048
#define DD 1024
#define NH 16
#define HDD 64

typedef __attribute__((ext_vector_type(8))) short v8s;     // 8 bf16 in 4 VGPRs
typedef __attribute__((ext_vector_type(4))) short v4s;     // 4 bf16 in 2 VGPRs
typedef __attribute__((ext_vector_type(4))) float f32x4;   // MFMA C/D

__device__ __forceinline__ unsigned short f2bf(float f) {
    union { float f; unsigned int u; } c; c.f = f;
    unsigned int r = c.u + 0x7FFF + ((c.u >> 16) & 1);     // RNE
    return (unsigned short)(r >> 16);
}

// pack 4 floats -> 4 bf16 (RNE).  HW v_cvt_pk_bf16_f32 when available.
__device__ __forceinline__ v4s pack_bf16x4(float a, float b, float c, float d) {
#if __has_builtin(__builtin_amdgcn_cvt_pk_bf16_f32)
    auto lo = __builtin_amdgcn_cvt_pk_bf16_f32(a, b);      // 2 bf16 in 4B
    auto hi = __builtin_amdgcn_cvt_pk_bf16_f32(c, d);
    union { v4s v; struct { decltype(lo) l; decltype(hi) h; } p; } u;
    u.p.l = lo; u.p.h = hi;
    return u.v;
#else
    v4s r;
    r[0] = (short)f2bf(a); r[1] = (short)f2bf(b);
    r[2] = (short)f2bf(c); r[3] = (short)f2bf(d);
    return r;
#endif
}

// raw 2^x (v_exp_f32).
__device__ __forceinline__ float fexp2(float x) {
#if __has_builtin(__builtin_amdgcn_exp2f)
    return __builtin_amdgcn_exp2f(x);
#else
    float r; asm("v_exp_f32 %0, %1" : "=v"(r) : "v"(x)); return r;
#endif
}

__device__ __forceinline__ void gload_lds16(const void* g, void* l) {
    __builtin_amdgcn_global_load_lds(
        (const __attribute__((address_space(1))) void*)g,
        (__attribute__((address_space(3))) void*)l, 16, 0, 0);
}

// K=16 bf16 MFMA (v_mfma_f32_16x16x16_bf16: A/B = 4 bf16, C/D = 4 f32).
__device__ __forceinline__ f32x4 mfma16x16x16bf16(v4s a, v4s b, f32x4 c) {
#if __has_builtin(__builtin_amdgcn_mfma_f32_16x16x16bf16_1k)
    return __builtin_amdgcn_mfma_f32_16x16x16bf16_1k(a, b, c, 0, 0, 0);
#else
    f32x4 d;
    asm("v_mfma_f32_16x16x16_bf16 %0, %1, %2, %0"
        : "=v"(d) : "v"(a), "v"(b), "0"(c));
    return d;
#endif
}

// ============================================================================
// Cast fp32 -> bf16 for x, Wq, Wk, Wv, Wo (blockIdx.y selects tensor).
// ============================================================================
__global__ __launch_bounds__(256) void cast5_kernel(
    const float* __restrict__ x, const float* __restrict__ wq,
    const float* __restrict__ wk, const float* __restrict__ wv,
    const float* __restrict__ wo,
    unsigned short* __restrict__ xo, unsigned short* __restrict__ wqo,
    unsigned short* __restrict__ wko, unsigned short* __restrict__ wvo,
    unsigned short* __restrict__ woo)
{
    const float* s; unsigned short* d; int n4;
    switch (blockIdx.y) {
        case 0: s = x;  d = xo;  n4 = BB * TT * DD / 4; break;
        case 1: s = wq; d = wqo; n4 = DD * DD / 4; break;
        case 2: s = wk; d = wko; n4 = DD * DD / 4; break;
        case 3: s = wv; d = wvo; n4 = DD * DD / 4; break;
        default: s = wo; d = woo; n4 = DD * DD / 4; break;
    }
    int i = blockIdx.x * 256 + threadIdx.x;
    if (i < n4) {
        float4 v = ((const float4*)s)[i];
        ushort4 o;
        o.x = f2bf(v.x); o.y = f2bf(v.y); o.z = f2bf(v.z); o.w = f2bf(v.w);
        ((ushort4*)d)[i] = o;
    }
}

// ============================================================================
// QKV projection, R7: tile 128x64 (was 128x128) -> grid (32,48) = 1536
// blocks ~= 5-6/CU (was 768 = exactly 3/CU).  Diagnosis: all pipes idle
// (MfmaUtil 16, VALU 8, HBM 12%, LDS ~30%) => per-iteration latency convoy
// at the __syncthreads vmcnt-drain; the grid itself capped TLP.  Smaller
// tiles keep the proven dbuf/syncthreads loop and staging math (no sync or
// swizzle changes), acc 4x2 per wave, 3 stage-loads/thread, LDS 24 KB.
// K pre-scaled by 0.125*log2e for the base-2 softmax downstream.
// ============================================================================
__global__ __launch_bounds__(256, 5) void qkv_mfma(
    const unsigned short* __restrict__ x,
    const unsigned short* __restrict__ wq, const unsigned short* __restrict__ wk,
    const unsigned short* __restrict__ wv,
    unsigned short* __restrict__ qo, unsigned short* __restrict__ ko,
    unsigned short* __restrict__ vo)
{
    __shared__ unsigned short SMEM[12288];    // 24 KB: A 2x8KB + B 2x4KB

    const int tid = threadIdx.x;
    const int lane = tid & 63;
    const int wid = tid >> 6;
    const int l15 = lane & 15, quad = lane >> 4;

    const int m0 = blockIdx.x << 7;           // 128 m-rows
    const int ny = blockIdx.y;                // 0..47
    const int which = ny >> 4;                // 0=q 1=k 2=v
    const int n0 = (ny & 15) << 6;            // 64 n-rows
    const unsigned short* W = (which == 0) ? wq : (which == 1) ? wk : wv;

    const int wm = (wid >> 1) << 6;           // 0 / 64
    const int wn = (wid & 1) << 5;            // 0 / 32

    // staging: thread covers A rows srow, srow+64 and B row srow (16B chunks)
    const int srow = tid >> 2;                // 0..63
    const int cs = (tid & 3) << 3;            // chunk col (ushorts)
    const int csw = cs ^ ((srow & 3) << 3);   // chunk-XOR (same for srow+64)
    const int fA = tid << 4;                  // linear byte offset
    const int rcol = ((quad ^ (l15 & 3)) << 4);   // read-side byte col

    char* const smem = (char*)SMEM;

#define QKV_STAGE(k0, buf)                                                     \
    do {                                                                       \
        gload_lds16(&x[(size_t)(m0 + srow) * DD + (k0) + csw],                 \
                    smem + (buf) * 8192 + fA);                                 \
        gload_lds16(&x[(size_t)(m0 + srow + 64) * DD + (k0) + csw],            \
                    smem + (buf) * 8192 + fA + 4096);                          \
        gload_lds16(&W[(size_t)(n0 + srow) * DD + (k0) + csw],                 \
                    smem + 16384 + (buf) * 4096 + fA);                         \
    } while (0)

    f32x4 acc[4][2] = {};

    QKV_STAGE(0, 0);
    __syncthreads();

    int cur = 0;
    for (int k0 = 0; k0 < DD; k0 += 32) {
        if (k0 + 32 < DD) QKV_STAGE(k0 + 32, cur ^ 1);

        const char* Ab = smem + cur * 8192;
        const char* Bb = smem + 16384 + cur * 4096;
        v8s af[4], bf[2];
#pragma unroll
        for (int i = 0; i < 4; ++i)
            af[i] = *(const v8s*)(Ab + (wm + (i << 4) + l15) * 64 + rcol);
#pragma unroll
        for (int j = 0; j < 2; ++j)
            bf[j] = *(const v8s*)(Bb + (wn + (j << 4) + l15) * 64 + rcol);
#pragma unroll
        for (int i = 0; i < 4; ++i)
#pragma unroll
            for (int j = 0; j < 2; ++j)
                acc[i][j] = __builtin_amdgcn_mfma_f32_16x16x32_bf16(af[i], bf[j], acc[i][j], 0, 0, 0);

        __syncthreads();
        cur ^= 1;
    }
#undef QKV_STAGE

    if (which == 2) {
#pragma unroll
        for (int i = 0; i < 4; ++i)
#pragma unroll
            for (int j = 0; j < 2; ++j) {
                const int n = n0 + wn + (j << 4) + l15;
                const int h = n >> 6, hd = n & 63;
                const int mb = m0 + wm + (i << 4) + (quad << 2);
                const int b = mb >> 11, t = mb & 2047;
                ushort4 pk;
                pk.x = f2bf(acc[i][j][0]); pk.y = f2bf(acc[i][j][1]);
                pk.z = f2bf(acc[i][j][2]); pk.w = f2bf(acc[i][j][3]);
                *(ushort4*)&vo[((((size_t)(b * NH + h) << 6) + hd) << 11) + t] = pk;
            }
    } else {
        unsigned short* outp = (which == 0) ? qo : ko;
        // K pre-scale: 1/sqrt(64) * log2(e) -> softmax in base 2 downstream
        const float sc = (which == 1) ? 0.18033688011112042f : 1.0f;
#pragma unroll
        for (int p = 0; p < 2; ++p) {
            __syncthreads();
            if ((wid >> 1) == p) {
#pragma unroll
                for (int i = 0; i < 4; ++i)
#pragma unroll
                    for (int j = 0; j < 2; ++j)
#pragma unroll
                        for (int r = 0; r < 4; ++r) {
                            const int row = (i << 4) + (quad << 2) + r;
                            SMEM[row * 72 + wn + (j << 4) + l15] = f2bf(acc[i][j][r] * sc);
                        }
            }
            __syncthreads();
            const int rr = tid >> 2;              // 0..63
            const int cg = (tid & 3) << 4;        // 0,16,32,48
            const int m = m0 + (p << 6) + rr;
            const int b = m >> 11, t = m & 2047;
#pragma unroll
            for (int k2 = 0; k2 < 2; ++k2) {
                const int col = cg + (k2 << 3);
                const int n = n0 + col;
                const int h = n >> 6, hd = n & 63;
                const uint4 val = *(const uint4*)&SMEM[rr * 72 + col];
                *(uint4*)&outp[(((size_t)(b * NH + h) * TT + t) << 6) + hd] = val;
            }
        }
    }
}

// ============================================================================
// Flash attention (unchanged from R6): 64-row Q tiles, grid 32x32, [64][64]
// LDS tiles with 16B-chunk row-XOR swizzle, base-2 online softmax.
// ============================================================================
__global__ __launch_bounds__(256) void attn_mfma(
    const unsigned short* __restrict__ q, const unsigned short* __restrict__ k,
    const unsigned short* __restrict__ vt, unsigned short* __restrict__ ctx)
{
    __shared__ unsigned short Qs[64][64];
    __shared__ unsigned short Ks[2][64][64];
    __shared__ unsigned short Vts[2][64][64];

    const int tid = threadIdx.x;
    const int lane = tid & 63;
    const int wid = tid >> 6;
    const int l15 = lane & 15, quad = lane >> 4;
    const int r7 = (l15 & 7) << 3;      // read-side row-XOR term (ushorts)

    const int bh = blockIdx.x;
    const int qt = 31 - (int)blockIdx.y;      // longest blocks dispatch first
    const int q0 = qt << 6;
    const int qrow = q0 + (wid << 4) + l15;   // this lane's q-row

    const unsigned short* qb = q + (size_t)bh * TT * HDD;
    const unsigned short* kb = k + (size_t)bh * TT * HDD;
    const unsigned short* vb = vt + (size_t)bh * HDD * TT;   // (HD, T)
    unsigned short* cb = ctx + (size_t)bh * TT * HDD;

    const int cr = tid >> 3;            // staging row 0..31 (x2 rounds)
    const int cc = (tid & 7) << 3;      // staging col (ushort), 16B chunks
    const int cs = cc ^ ((cr & 7) << 3);  // swizzled store col (row&7 XOR)

    // Q tile + K/V tile 0 -> LDS (swizzled stores)
#pragma unroll
    for (int u = 0; u < 2; ++u) {
        const int r = cr + (u << 5);
        *(uint4*)&Qs[r][cs] = *(const uint4*)&qb[(size_t)(q0 + r) * HDD + cc];
    }
    {
        uint4 k0r = *(const uint4*)&kb[(size_t)cr * HDD + cc];
        uint4 k1r = *(const uint4*)&kb[(size_t)(cr + 32) * HDD + cc];
        uint4 v0r = *(const uint4*)&vb[((size_t)cr << 11) + cc];
        uint4 v1r = *(const uint4*)&vb[((size_t)(cr + 32) << 11) + cc];
        *(uint4*)&Ks[0][cr][cs] = k0r;
        *(uint4*)&Ks[0][cr + 32][cs] = k1r;
        *(uint4*)&Vts[0][cr][cs] = v0r;
        *(uint4*)&Vts[0][cr + 32][cs] = v1r;
    }
    __syncthreads();

    // Q B-frags, wave-resident for the k-loop (swizzled reads)
    v8s qf[2];
#pragma unroll
    for (int c = 0; c < 2; ++c)
        qf[c] = *(const v8s*)&Qs[(wid << 4) + l15]
                               [(((c << 5) + (quad << 3)) ^ r7)];

    float m_i = -INFINITY, l_i = 0.f;
    f32x4 o[4] = {};                    // O^T: d = m*16 + quad*4 + r, col q=l15

    for (int jt = 0; jt <= qt; ++jt) {
        const int cur = jt & 1;

        // issue global loads for tile jt+1 (land during compute below)
        uint4 k0r, k1r, v0r, v1r;
        const bool pre = (jt < qt);
        if (pre) {
            const int kn = (jt + 1) << 6;
            k0r = *(const uint4*)&kb[(size_t)(kn + cr) * HDD + cc];
            k1r = *(const uint4*)&kb[(size_t)(kn + cr + 32) * HDD + cc];
            v0r = *(const uint4*)&vb[((size_t)cr << 11) + kn + cc];
            v1r = *(const uint4*)&vb[((size_t)(cr + 32) << 11) + kn + cc];
        }

        const int k0 = jt << 6;

        // S^T = K . Q^T : St[k = m*16+quad*4+r][q = l15]
        f32x4 s[4] = {};
        const int kc0 = (quad << 3) ^ r7;         // kf0 col
#pragma unroll
        for (int m = 0; m < 4; ++m) {
            const v8s kf0 = *(const v8s*)&Ks[cur][(m << 4) + l15][kc0];
            const v8s kf1 = *(const v8s*)&Ks[cur][(m << 4) + l15][kc0 ^ 32];
            s[m] = __builtin_amdgcn_mfma_f32_16x16x32_bf16(kf0, qf[0], s[m], 0, 0, 0);
            s[m] = __builtin_amdgcn_mfma_f32_16x16x32_bf16(kf1, qf[1], s[m], 0, 0, 0);
        }

        if (jt == qt) {                 // causal mask, diagonal tile only
#pragma unroll
            for (int m = 0; m < 4; ++m) {
                const int kc = k0 + (m << 4) + (quad << 2);
#pragma unroll
                for (int r = 0; r < 4; ++r)
                    if (kc + r > qrow) s[m][r] = -INFINITY;
            }
        }

        // online softmax (base 2): one q-row per lane, 2 shfl for row-max
        float mx = fmaxf(fmaxf(s[0][0], s[0][1]), fmaxf(s[0][2], s[0][3]));
        mx = fmaxf(mx, fmaxf(fmaxf(s[1][0], s[1][1]), fmaxf(s[1][2], s[1][3])));
        mx = fmaxf(mx, fmaxf(fmaxf(s[2][0], s[2][1]), fmaxf(s[2][2], s[2][3])));
        mx = fmaxf(mx, fmaxf(fmaxf(s[3][0], s[3][1]), fmaxf(s[3][2], s[3][3])));
        mx = fmaxf(mx, __shfl_xor(mx, 16));
        mx = fmaxf(mx, __shfl_xor(mx, 32));
        const float m_new = fmaxf(m_i, mx);
        const float alpha = fexp2(m_i - m_new);
        m_i = m_new;

        float sum = 0.f;
        v4s pf[4];
#pragma unroll
        for (int m = 0; m < 4; ++m) {
            const float p0 = fexp2(s[m][0] - m_new);
            const float p1 = fexp2(s[m][1] - m_new);
            const float p2 = fexp2(s[m][2] - m_new);
            const float p3 = fexp2(s[m][3] - m_new);
            sum += (p0 + p1) + (p2 + p3);
            pf[m] = pack_bf16x4(p0, p1, p2, p3);
        }
        sum += __shfl_xor(sum, 16);
        sum += __shfl_xor(sum, 32);
        l_i = l_i * alpha + sum;

#pragma unroll
        for (int m = 0; m < 4; ++m)
#pragma unroll
            for (int r = 0; r < 4; ++r)
                o[m][r] *= alpha;

        // O^T += Vt . P^T  (swizzled b64 reads)
#pragma unroll
        for (int m = 0; m < 4; ++m)
#pragma unroll
            for (int c = 0; c < 4; ++c) {
                const v4s vf = *(const v4s*)&Vts[cur][(m << 4) + l15]
                                                    [(((c << 4) + (quad << 2)) ^ r7)];
                o[m] = mfma16x16x16bf16(vf, pf[c], o[m]);
            }

        // publish tile jt+1 into the other buffer (swizzled stores)
        if (pre) {
            const int nxt = cur ^ 1;
            *(uint4*)&Ks[nxt][cr][cs] = k0r;
            *(uint4*)&Ks[nxt][cr + 32][cs] = k1r;
            *(uint4*)&Vts[nxt][cr][cs] = v0r;
            *(uint4*)&Vts[nxt][cr + 32][cs] = v1r;
        }
        __syncthreads();
    }

    // normalize + store: ctx[q][d], d = m*16 + quad*4 + r (8B stores)
    const float linv = 1.f / l_i;
#pragma unroll
    for (int m = 0; m < 4; ++m) {
        ushort4 st;
        st.x = f2bf(o[m][0] * linv); st.y = f2bf(o[m][1] * linv);
        st.z = f2bf(o[m][2] * linv); st.w = f2bf(o[m][3] * linv);
        *(ushort4*)&cb[((size_t)qrow << 6) + (m << 4) + (quad << 2)] = st;
    }
}

// ============================================================================
// Output projection, R7: tile 64x64 -> grid (64,16) = 1024 blocks = 4/CU
// (was 256 = 1/CU, fully latency-exposed).  Same dbuf loop; acc 2x2/wave.
// ============================================================================
__global__ __launch_bounds__(256) void oproj_mfma(
    const unsigned short* __restrict__ c, const unsigned short* __restrict__ wo,
    const float* __restrict__ bo, float* __restrict__ out)
{
    __shared__ unsigned short SMEM[8192];     // 16 KB: A 2x4KB + B 2x4KB

    const int tid = threadIdx.x;
    const int lane = tid & 63;
    const int wid = tid >> 6;
    const int l15 = lane & 15, quad = lane >> 4;

    const int m0 = blockIdx.x << 6;           // 64 m-rows
    const int n0 = blockIdx.y << 6;           // 64 n-rows
    const int wm = (wid >> 1) << 5, wn = (wid & 1) << 5;

    const int srow = tid >> 2;                // 0..63
    const int csst = (tid & 3) << 3;
    const int csw = csst ^ ((srow & 3) << 3);
    const int fA = tid << 4;
    const int rcol = ((quad ^ (l15 & 3)) << 4);

    char* const smem = (char*)SMEM;

#define OP_STAGE(k0, buf)                                                      \
    do {                                                                       \
        gload_lds16(&c[(size_t)(m0 + srow) * DD + (k0) + csw],                 \
                    smem + (buf) * 4096 + fA);                                 \
        gload_lds16(&wo[(size_t)(n0 + srow) * DD + (k0) + csw],                \
                    smem + 8192 + (buf) * 4096 + fA);                          \
    } while (0)

    f32x4 acc[2][2] = {};

    OP_STAGE(0, 0);
    __syncthreads();

    int cur = 0;
    for (int k0 = 0; k0 < DD; k0 += 32) {
        if (k0 + 32 < DD) OP_STAGE(k0 + 32, cur ^ 1);

        const char* Ab = smem + cur * 4096;
        const char* Bb = smem + 8192 + cur * 4096;
        v8s af[2], bf[2];
#pragma unroll
        for (int i = 0; i < 2; ++i)
            af[i] = *(const v8s*)(Ab + (wm + (i << 4) + l15) * 64 + rcol);
#pragma unroll
        for (int j = 0; j < 2; ++j)
            bf[j] = *(const v8s*)(Bb + (wn + (j << 4) + l15) * 64 + rcol);
#pragma unroll
        for (int i = 0; i < 2; ++i)
#pragma unroll
            for (int j = 0; j < 2; ++j)
                acc[i][j] = __builtin_amdgcn_mfma_f32_16x16x32_bf16(af[i], bf[j], acc[i][j], 0, 0, 0);

        __syncthreads();
        cur ^= 1;
    }
#undef OP_STAGE

#pragma unroll
    for (int j = 0; j < 2; ++j) {
        const int n = n0 + wn + (j << 4) + l15;
        const float bias = bo[n];
#pragma unroll
        for (int i = 0; i < 2; ++i) {
            const int mb = m0 + wm + (i << 4) + (quad << 2);
#pragma unroll
            for (int r = 0; r < 4; ++r)
                out[(size_t)(mb + r) * DD + n] = acc[i][j][r] + bias;
        }
    }
}

extern "C" void kernel_launch(void* const* d_in, const int* in_sizes, int n_in,
                              void* d_out, int out_size, void* d_ws, size_t ws_size,
                              hipStream_t stream) {
    const float* x  = (const float*)d_in[0];
    const float* Wq = (const float*)d_in[1];
    const float* Wk = (const float*)d_in[2];
    const float* Wv = (const float*)d_in[3];
    const float* Wo = (const float*)d_in[4];
    const float* bo = (const float*)d_in[5];
    float* out = (float*)d_out;

    const size_t NX = (size_t)BB * TT * DD;
    const size_t NW = (size_t)DD * DD;

    unsigned short* xb  = (unsigned short*)d_ws;
    unsigned short* wqb = xb + NX;
    unsigned short* wkb = wqb + NW;
    unsigned short* wvb = wkb + NW;
    unsigned short* wob = wvb + NW;
    unsigned short* qb  = wob + NW;
    unsigned short* kb  = qb + NX;
    unsigned short* vtb = kb + NX;
    unsigned short* cbuf = vtb + NX;

    cast5_kernel<<<dim3(4096, 5), 256, 0, stream>>>(x, Wq, Wk, Wv, Wo,
                                                    xb, wqb, wkb, wvb, wob);
    qkv_mfma<<<dim3(32, 48), 256, 0, stream>>>(xb, wqb, wkb, wvb, qb, kb, vtb);
    attn_mfma<<<dim3(32, 32), 256, 0, stream>>>(qb, kb, vtb, cbuf);
    oproj_mfma<<<dim3(64, 16), 256, 0, stream>>>(cbuf, wob, bo, out);
}

// Round 8
// 184.678 us; speedup vs baseline: 1.0097x; 1.0097x over previous
//
#include <hip/hip_runtime.h>
#include <math.h>

#define BB 2
#define TT 2048
#define DD 1024
#define NH 16
#define HDD 64

typedef __attribute__((ext_vector_type(8))) short v8s;     // 8 bf16 in 4 VGPRs
typedef __attribute__((ext_vector_type(4))) short v4s;     // 4 bf16 in 2 VGPRs
typedef __attribute__((ext_vector_type(4))) float f32x4;   // MFMA C/D

__device__ __forceinline__ unsigned short f2bf(float f) {
    union { float f; unsigned int u; } c; c.f = f;
    unsigned int r = c.u + 0x7FFF + ((c.u >> 16) & 1);     // RNE
    return (unsigned short)(r >> 16);
}

// pack 4 floats -> 4 bf16 (RNE).  HW v_cvt_pk_bf16_f32 when available.
__device__ __forceinline__ v4s pack_bf16x4(float a, float b, float c, float d) {
#if __has_builtin(__builtin_amdgcn_cvt_pk_bf16_f32)
    auto lo = __builtin_amdgcn_cvt_pk_bf16_f32(a, b);      // 2 bf16 in 4B
    auto hi = __builtin_amdgcn_cvt_pk_bf16_f32(c, d);
    union { v4s v; struct { decltype(lo) l; decltype(hi) h; } p; } u;
    u.p.l = lo; u.p.h = hi;
    return u.v;
#else
    v4s r;
    r[0] = (short)f2bf(a); r[1] = (short)f2bf(b);
    r[2] = (short)f2bf(c); r[3] = (short)f2bf(d);
    return r;
#endif
}

// raw 2^x (v_exp_f32).
__device__ __forceinline__ float fexp2(float x) {
#if __has_builtin(__builtin_amdgcn_exp2f)
    return __builtin_amdgcn_exp2f(x);
#else
    float r; asm("v_exp_f32 %0, %1" : "=v"(r) : "v"(x)); return r;
#endif
}

__device__ __forceinline__ void gload_lds16(const void* g, void* l) {
    __builtin_amdgcn_global_load_lds(
        (const __attribute__((address_space(1))) void*)g,
        (__attribute__((address_space(3))) void*)l, 16, 0, 0);
}

// K=16 bf16 MFMA (v_mfma_f32_16x16x16_bf16: A/B = 4 bf16, C/D = 4 f32).
__device__ __forceinline__ f32x4 mfma16x16x16bf16(v4s a, v4s b, f32x4 c) {
#if __has_builtin(__builtin_amdgcn_mfma_f32_16x16x16bf16_1k)
    return __builtin_amdgcn_mfma_f32_16x16x16bf16_1k(a, b, c, 0, 0, 0);
#else
    f32x4 d;
    asm("v_mfma_f32_16x16x16_bf16 %0, %1, %2, %0"
        : "=v"(d) : "v"(a), "v"(b), "0"(c));
    return d;
#endif
}

// ============================================================================
// Cast fp32 -> bf16 for x, Wq, Wk, Wv, Wo (blockIdx.y selects tensor).
// ============================================================================
__global__ __launch_bounds__(256) void cast5_kernel(
    const float* __restrict__ x, const float* __restrict__ wq,
    const float* __restrict__ wk, const float* __restrict__ wv,
    const float* __restrict__ wo,
    unsigned short* __restrict__ xo, unsigned short* __restrict__ wqo,
    unsigned short* __restrict__ wko, unsigned short* __restrict__ wvo,
    unsigned short* __restrict__ woo)
{
    const float* s; unsigned short* d; int n4;
    switch (blockIdx.y) {
        case 0: s = x;  d = xo;  n4 = BB * TT * DD / 4; break;
        case 1: s = wq; d = wqo; n4 = DD * DD / 4; break;
        case 2: s = wk; d = wko; n4 = DD * DD / 4; break;
        case 3: s = wv; d = wvo; n4 = DD * DD / 4; break;
        default: s = wo; d = woo; n4 = DD * DD / 4; break;
    }
    int i = blockIdx.x * 256 + threadIdx.x;
    if (i < n4) {
        float4 v = ((const float4*)s)[i];
        ushort4 o;
        o.x = f2bf(v.x); o.y = f2bf(v.y); o.z = f2bf(v.z); o.w = f2bf(v.w);
        ((ushort4*)d)[i] = o;
    }
}

// ============================================================================
// QKV projection, R8: same 128x64 tiles / grid (32,48) as R7, with the
// bank swizzle corrected from  chunk ^= row&3  to  chunk ^= (row>>1)&3.
// Derivation: rows are 64B (= half the 32-bank span), so a b128 read's
// bank-group is (chunk, row-parity).  l15&1 is a subset of l15&3, so the
// old XOR used only 4 of 8 groups -> 4-way conflict (measured 4.78M).
// (row>>1)&3 makes (chunk,parity) bijective over 8 groups, 2 lanes each
// -> 2-way = free.  Valid since fragment rows === l15 (mod 16) and staging
// rows srow/srow+64 share (srow>>1)&3.
// K pre-scaled by 0.125*log2e for the base-2 softmax downstream.
// ============================================================================
__global__ __launch_bounds__(256, 5) void qkv_mfma(
    const unsigned short* __restrict__ x,
    const unsigned short* __restrict__ wq, const unsigned short* __restrict__ wk,
    const unsigned short* __restrict__ wv,
    unsigned short* __restrict__ qo, unsigned short* __restrict__ ko,
    unsigned short* __restrict__ vo)
{
    __shared__ unsigned short SMEM[12288];    // 24 KB: A 2x8KB + B 2x4KB

    const int tid = threadIdx.x;
    const int lane = tid & 63;
    const int wid = tid >> 6;
    const int l15 = lane & 15, quad = lane >> 4;

    const int m0 = blockIdx.x << 7;           // 128 m-rows
    const int ny = blockIdx.y;                // 0..47
    const int which = ny >> 4;                // 0=q 1=k 2=v
    const int n0 = (ny & 15) << 6;            // 64 n-rows
    const unsigned short* W = (which == 0) ? wq : (which == 1) ? wk : wv;

    const int wm = (wid >> 1) << 6;           // 0 / 64
    const int wn = (wid & 1) << 5;            // 0 / 32

    // staging: thread covers A rows srow, srow+64 and B row srow (16B chunks)
    const int srow = tid >> 2;                // 0..63
    const int cs = (tid & 3) << 3;            // chunk col (ushorts)
    const int csw = cs ^ (((srow >> 1) & 3) << 3);   // (row>>1)&3 chunk-XOR
    const int fA = tid << 4;                  // linear byte offset
    const int rcol = ((quad ^ ((l15 >> 1) & 3)) << 4);   // read-side byte col

    char* const smem = (char*)SMEM;

#define QKV_STAGE(k0, buf)                                                     \
    do {                                                                       \
        gload_lds16(&x[(size_t)(m0 + srow) * DD + (k0) + csw],                 \
                    smem + (buf) * 8192 + fA);                                 \
        gload_lds16(&x[(size_t)(m0 + srow + 64) * DD + (k0) + csw],            \
                    smem + (buf) * 8192 + fA + 4096);                          \
        gload_lds16(&W[(size_t)(n0 + srow) * DD + (k0) + csw],                 \
                    smem + 16384 + (buf) * 4096 + fA);                         \
    } while (0)

    f32x4 acc[4][2] = {};

    QKV_STAGE(0, 0);
    __syncthreads();

    int cur = 0;
    for (int k0 = 0; k0 < DD; k0 += 32) {
        if (k0 + 32 < DD) QKV_STAGE(k0 + 32, cur ^ 1);

        const char* Ab = smem + cur * 8192;
        const char* Bb = smem + 16384 + cur * 4096;
        v8s af[4], bf[2];
#pragma unroll
        for (int i = 0; i < 4; ++i)
            af[i] = *(const v8s*)(Ab + (wm + (i << 4) + l15) * 64 + rcol);
#pragma unroll
        for (int j = 0; j < 2; ++j)
            bf[j] = *(const v8s*)(Bb + (wn + (j << 4) + l15) * 64 + rcol);
#pragma unroll
        for (int i = 0; i < 4; ++i)
#pragma unroll
            for (int j = 0; j < 2; ++j)
                acc[i][j] = __builtin_amdgcn_mfma_f32_16x16x32_bf16(af[i], bf[j], acc[i][j], 0, 0, 0);

        __syncthreads();
        cur ^= 1;
    }
#undef QKV_STAGE

    if (which == 2) {
#pragma unroll
        for (int i = 0; i < 4; ++i)
#pragma unroll
            for (int j = 0; j < 2; ++j) {
                const int n = n0 + wn + (j << 4) + l15;
                const int h = n >> 6, hd = n & 63;
                const int mb = m0 + wm + (i << 4) + (quad << 2);
                const int b = mb >> 11, t = mb & 2047;
                ushort4 pk;
                pk.x = f2bf(acc[i][j][0]); pk.y = f2bf(acc[i][j][1]);
                pk.z = f2bf(acc[i][j][2]); pk.w = f2bf(acc[i][j][3]);
                *(ushort4*)&vo[((((size_t)(b * NH + h) << 6) + hd) << 11) + t] = pk;
            }
    } else {
        unsigned short* outp = (which == 0) ? qo : ko;
        // K pre-scale: 1/sqrt(64) * log2(e) -> softmax in base 2 downstream
        const float sc = (which == 1) ? 0.18033688011112042f : 1.0f;
#pragma unroll
        for (int p = 0; p < 2; ++p) {
            __syncthreads();
            if ((wid >> 1) == p) {
#pragma unroll
                for (int i = 0; i < 4; ++i)
#pragma unroll
                    for (int j = 0; j < 2; ++j)
#pragma unroll
                        for (int r = 0; r < 4; ++r) {
                            const int row = (i << 4) + (quad << 2) + r;
                            SMEM[row * 72 + wn + (j << 4) + l15] = f2bf(acc[i][j][r] * sc);
                        }
            }
            __syncthreads();
            const int rr = tid >> 2;              // 0..63
            const int cg = (tid & 3) << 4;        // 0,16,32,48
            const int m = m0 + (p << 6) + rr;
            const int b = m >> 11, t = m & 2047;
#pragma unroll
            for (int k2 = 0; k2 < 2; ++k2) {
                const int col = cg + (k2 << 3);
                const int n = n0 + col;
                const int h = n >> 6, hd = n & 63;
                const uint4 val = *(const uint4*)&SMEM[rr * 72 + col];
                *(uint4*)&outp[(((size_t)(b * NH + h) * TT + t) << 6) + hd] = val;
            }
        }
    }
}

// ============================================================================
// Flash attention (unchanged from R6): 64-row Q tiles, grid 32x32, [64][64]
// LDS tiles with 16B-chunk row-XOR swizzle, base-2 online softmax.
// ============================================================================
__global__ __launch_bounds__(256) void attn_mfma(
    const unsigned short* __restrict__ q, const unsigned short* __restrict__ k,
    const unsigned short* __restrict__ vt, unsigned short* __restrict__ ctx)
{
    __shared__ unsigned short Qs[64][64];
    __shared__ unsigned short Ks[2][64][64];
    __shared__ unsigned short Vts[2][64][64];

    const int tid = threadIdx.x;
    const int lane = tid & 63;
    const int wid = tid >> 6;
    const int l15 = lane & 15, quad = lane >> 4;
    const int r7 = (l15 & 7) << 3;      // read-side row-XOR term (ushorts)

    const int bh = blockIdx.x;
    const int qt = 31 - (int)blockIdx.y;      // longest blocks dispatch first
    const int q0 = qt << 6;
    const int qrow = q0 + (wid << 4) + l15;   // this lane's q-row

    const unsigned short* qb = q + (size_t)bh * TT * HDD;
    const unsigned short* kb = k + (size_t)bh * TT * HDD;
    const unsigned short* vb = vt + (size_t)bh * HDD * TT;   // (HD, T)
    unsigned short* cb = ctx + (size_t)bh * TT * HDD;

    const int cr = tid >> 3;            // staging row 0..31 (x2 rounds)
    const int cc = (tid & 7) << 3;      // staging col (ushort), 16B chunks
    const int cs = cc ^ ((cr & 7) << 3);  // swizzled store col (row&7 XOR)

    // Q tile + K/V tile 0 -> LDS (swizzled stores)
#pragma unroll
    for (int u = 0; u < 2; ++u) {
        const int r = cr + (u << 5);
        *(uint4*)&Qs[r][cs] = *(const uint4*)&qb[(size_t)(q0 + r) * HDD + cc];
    }
    {
        uint4 k0r = *(const uint4*)&kb[(size_t)cr * HDD + cc];
        uint4 k1r = *(const uint4*)&kb[(size_t)(cr + 32) * HDD + cc];
        uint4 v0r = *(const uint4*)&vb[((size_t)cr << 11) + cc];
        uint4 v1r = *(const uint4*)&vb[((size_t)(cr + 32) << 11) + cc];
        *(uint4*)&Ks[0][cr][cs] = k0r;
        *(uint4*)&Ks[0][cr + 32][cs] = k1r;
        *(uint4*)&Vts[0][cr][cs] = v0r;
        *(uint4*)&Vts[0][cr + 32][cs] = v1r;
    }
    __syncthreads();

    // Q B-frags, wave-resident for the k-loop (swizzled reads)
    v8s qf[2];
#pragma unroll
    for (int c = 0; c < 2; ++c)
        qf[c] = *(const v8s*)&Qs[(wid << 4) + l15]
                               [(((c << 5) + (quad << 3)) ^ r7)];

    float m_i = -INFINITY, l_i = 0.f;
    f32x4 o[4] = {};                    // O^T: d = m*16 + quad*4 + r, col q=l15

    for (int jt = 0; jt <= qt; ++jt) {
        const int cur = jt & 1;

        // issue global loads for tile jt+1 (land during compute below)
        uint4 k0r, k1r, v0r, v1r;
        const bool pre = (jt < qt);
        if (pre) {
            const int kn = (jt + 1) << 6;
            k0r = *(const uint4*)&kb[(size_t)(kn + cr) * HDD + cc];
            k1r = *(const uint4*)&kb[(size_t)(kn + cr + 32) * HDD + cc];
            v0r = *(const uint4*)&vb[((size_t)cr << 11) + kn + cc];
            v1r = *(const uint4*)&vb[((size_t)(cr + 32) << 11) + kn + cc];
        }

        const int k0 = jt << 6;

        // S^T = K . Q^T : St[k = m*16+quad*4+r][q = l15]
        f32x4 s[4] = {};
        const int kc0 = (quad << 3) ^ r7;         // kf0 col
#pragma unroll
        for (int m = 0; m < 4; ++m) {
            const v8s kf0 = *(const v8s*)&Ks[cur][(m << 4) + l15][kc0];
            const v8s kf1 = *(const v8s*)&Ks[cur][(m << 4) + l15][kc0 ^ 32];
            s[m] = __builtin_amdgcn_mfma_f32_16x16x32_bf16(kf0, qf[0], s[m], 0, 0, 0);
            s[m] = __builtin_amdgcn_mfma_f32_16x16x32_bf16(kf1, qf[1], s[m], 0, 0, 0);
        }

        if (jt == qt) {                 // causal mask, diagonal tile only
#pragma unroll
            for (int m = 0; m < 4; ++m) {
                const int kc = k0 + (m << 4) + (quad << 2);
#pragma unroll
                for (int r = 0; r < 4; ++r)
                    if (kc + r > qrow) s[m][r] = -INFINITY;
            }
        }

        // online softmax (base 2): one q-row per lane, 2 shfl for row-max
        float mx = fmaxf(fmaxf(s[0][0], s[0][1]), fmaxf(s[0][2], s[0][3]));
        mx = fmaxf(mx, fmaxf(fmaxf(s[1][0], s[1][1]), fmaxf(s[1][2], s[1][3])));
        mx = fmaxf(mx, fmaxf(fmaxf(s[2][0], s[2][1]), fmaxf(s[2][2], s[2][3])));
        mx = fmaxf(mx, fmaxf(fmaxf(s[3][0], s[3][1]), fmaxf(s[3][2], s[3][3])));
        mx = fmaxf(mx, __shfl_xor(mx, 16));
        mx = fmaxf(mx, __shfl_xor(mx, 32));
        const float m_new = fmaxf(m_i, mx);
        const float alpha = fexp2(m_i - m_new);
        m_i = m_new;

        float sum = 0.f;
        v4s pf[4];
#pragma unroll
        for (int m = 0; m < 4; ++m) {
            const float p0 = fexp2(s[m][0] - m_new);
            const float p1 = fexp2(s[m][1] - m_new);
            const float p2 = fexp2(s[m][2] - m_new);
            const float p3 = fexp2(s[m][3] - m_new);
            sum += (p0 + p1) + (p2 + p3);
            pf[m] = pack_bf16x4(p0, p1, p2, p3);
        }
        sum += __shfl_xor(sum, 16);
        sum += __shfl_xor(sum, 32);
        l_i = l_i * alpha + sum;

#pragma unroll
        for (int m = 0; m < 4; ++m)
#pragma unroll
            for (int r = 0; r < 4; ++r)
                o[m][r] *= alpha;

        // O^T += Vt . P^T  (swizzled b64 reads)
#pragma unroll
        for (int m = 0; m < 4; ++m)
#pragma unroll
            for (int c = 0; c < 4; ++c) {
                const v4s vf = *(const v4s*)&Vts[cur][(m << 4) + l15]
                                                    [(((c << 4) + (quad << 2)) ^ r7)];
                o[m] = mfma16x16x16bf16(vf, pf[c], o[m]);
            }

        // publish tile jt+1 into the other buffer (swizzled stores)
        if (pre) {
            const int nxt = cur ^ 1;
            *(uint4*)&Ks[nxt][cr][cs] = k0r;
            *(uint4*)&Ks[nxt][cr + 32][cs] = k1r;
            *(uint4*)&Vts[nxt][cr][cs] = v0r;
            *(uint4*)&Vts[nxt][cr + 32][cs] = v1r;
        }
        __syncthreads();
    }

    // normalize + store: ctx[q][d], d = m*16 + quad*4 + r (8B stores)
    const float linv = 1.f / l_i;
#pragma unroll
    for (int m = 0; m < 4; ++m) {
        ushort4 st;
        st.x = f2bf(o[m][0] * linv); st.y = f2bf(o[m][1] * linv);
        st.z = f2bf(o[m][2] * linv); st.w = f2bf(o[m][3] * linv);
        *(ushort4*)&cb[((size_t)qrow << 6) + (m << 4) + (quad << 2)] = st;
    }
}

// ============================================================================
// Output projection, R8: 128x64 tiles (the structure R7 validated on qkv),
// grid (32,16) = 512 blocks = 2/CU.  Undoes R7's 64x64 regression (64x64
// doubled total K-panel traffic and worsened LDS-reads-per-MFMA to 1.0).
// acc 4x2/wave, LDS 24KB, corrected (row>>1)&3 swizzle.
// ============================================================================
__global__ __launch_bounds__(256) void oproj_mfma(
    const unsigned short* __restrict__ c, const unsigned short* __restrict__ wo,
    const float* __restrict__ bo, float* __restrict__ out)
{
    __shared__ unsigned short SMEM[12288];    // 24 KB: A 2x8KB + B 2x4KB

    const int tid = threadIdx.x;
    const int lane = tid & 63;
    const int wid = tid >> 6;
    const int l15 = lane & 15, quad = lane >> 4;

    const int m0 = blockIdx.x << 7;           // 128 m-rows
    const int n0 = blockIdx.y << 6;           // 64 n-rows
    const int wm = (wid >> 1) << 6;           // 0 / 64
    const int wn = (wid & 1) << 5;            // 0 / 32

    const int srow = tid >> 2;                // 0..63
    const int cs = (tid & 3) << 3;
    const int csw = cs ^ (((srow >> 1) & 3) << 3);
    const int fA = tid << 4;
    const int rcol = ((quad ^ ((l15 >> 1) & 3)) << 4);

    char* const smem = (char*)SMEM;

#define OP_STAGE(k0, buf)                                                      \
    do {                                                                       \
        gload_lds16(&c[(size_t)(m0 + srow) * DD + (k0) + csw],                 \
                    smem + (buf) * 8192 + fA);                                 \
        gload_lds16(&c[(size_t)(m0 + srow + 64) * DD + (k0) + csw],            \
                    smem + (buf) * 8192 + fA + 4096);                          \
        gload_lds16(&wo[(size_t)(n0 + srow) * DD + (k0) + csw],                \
                    smem + 16384 + (buf) * 4096 + fA);                         \
    } while (0)

    f32x4 acc[4][2] = {};

    OP_STAGE(0, 0);
    __syncthreads();

    int cur = 0;
    for (int k0 = 0; k0 < DD; k0 += 32) {
        if (k0 + 32 < DD) OP_STAGE(k0 + 32, cur ^ 1);

        const char* Ab = smem + cur * 8192;
        const char* Bb = smem + 16384 + cur * 4096;
        v8s af[4], bf[2];
#pragma unroll
        for (int i = 0; i < 4; ++i)
            af[i] = *(const v8s*)(Ab + (wm + (i << 4) + l15) * 64 + rcol);
#pragma unroll
        for (int j = 0; j < 2; ++j)
            bf[j] = *(const v8s*)(Bb + (wn + (j << 4) + l15) * 64 + rcol);
#pragma unroll
        for (int i = 0; i < 4; ++i)
#pragma unroll
            for (int j = 0; j < 2; ++j)
                acc[i][j] = __builtin_amdgcn_mfma_f32_16x16x32_bf16(af[i], bf[j], acc[i][j], 0, 0, 0);

        __syncthreads();
        cur ^= 1;
    }
#undef OP_STAGE

#pragma unroll
    for (int j = 0; j < 2; ++j) {
        const int n = n0 + wn + (j << 4) + l15;
        const float bias = bo[n];
#pragma unroll
        for (int i = 0; i < 4; ++i) {
            const int mb = m0 + wm + (i << 4) + (quad << 2);
#pragma unroll
            for (int r = 0; r < 4; ++r)
                out[(size_t)(mb + r) * DD + n] = acc[i][j][r] + bias;
        }
    }
}

extern "C" void kernel_launch(void* const* d_in, const int* in_sizes, int n_in,
                              void* d_out, int out_size, void* d_ws, size_t ws_size,
                              hipStream_t stream) {
    const float* x  = (const float*)d_in[0];
    const float* Wq = (const float*)d_in[1];
    const float* Wk = (const float*)d_in[2];
    const float* Wv = (const float*)d_in[3];
    const float* Wo = (const float*)d_in[4];
    const float* bo = (const float*)d_in[5];
    float* out = (float*)d_out;

    const size_t NX = (size_t)BB * TT * DD;
    const size_t NW = (size_t)DD * DD;

    unsigned short* xb  = (unsigned short*)d_ws;
    unsigned short* wqb = xb + NX;
    unsigned short* wkb = wqb + NW;
    unsigned short* wvb = wkb + NW;
    unsigned short* wob = wvb + NW;
    unsigned short* qb  = wob + NW;
    unsigned short* kb  = qb + NX;
    unsigned short* vtb = kb + NX;
    unsigned short* cbuf = vtb + NX;

    cast5_kernel<<<dim3(4096, 5), 256, 0, stream>>>(x, Wq, Wk, Wv, Wo,
                                                    xb, wqb, wkb, wvb, wob);
    qkv_mfma<<<dim3(32, 48), 256, 0, stream>>>(xb, wqb, wkb, wvb, qb, kb, vtb);
    attn_mfma<<<dim3(32, 32), 256, 0, stream>>>(qb, kb, vtb, cbuf);
    oproj_mfma<<<dim3(32, 16), 256, 0, stream>>>(cbuf, wob, bo, out);
}

// Round 9
// 169.270 us; speedup vs baseline: 1.1016x; 1.0910x over previous
//
#include <hip/hip_runtime.h>
#include <math.h>

#define BB 2
#define TT 2048
#define DD 1024
#define NH 16
#define HDD 64

typedef __attribute__((ext_vector_type(8))) short v8s;     // 8 bf16 in 4 VGPRs
typedef __attribute__((ext_vector_type(4))) short v4s;     // 4 bf16 in 2 VGPRs
typedef __attribute__((ext_vector_type(4))) float f32x4;   // MFMA C/D

__device__ __forceinline__ unsigned short f2bf(float f) {
    union { float f; unsigned int u; } c; c.f = f;
    unsigned int r = c.u + 0x7FFF + ((c.u >> 16) & 1);     // RNE
    return (unsigned short)(r >> 16);
}

// pack 4 floats -> 4 bf16 (RNE).  HW v_cvt_pk_bf16_f32 when available.
__device__ __forceinline__ v4s pack_bf16x4(float a, float b, float c, float d) {
#if __has_builtin(__builtin_amdgcn_cvt_pk_bf16_f32)
    auto lo = __builtin_amdgcn_cvt_pk_bf16_f32(a, b);      // 2 bf16 in 4B
    auto hi = __builtin_amdgcn_cvt_pk_bf16_f32(c, d);
    union { v4s v; struct { decltype(lo) l; decltype(hi) h; } p; } u;
    u.p.l = lo; u.p.h = hi;
    return u.v;
#else
    v4s r;
    r[0] = (short)f2bf(a); r[1] = (short)f2bf(b);
    r[2] = (short)f2bf(c); r[3] = (short)f2bf(d);
    return r;
#endif
}

// raw 2^x (v_exp_f32).
__device__ __forceinline__ float fexp2(float x) {
#if __has_builtin(__builtin_amdgcn_exp2f)
    return __builtin_amdgcn_exp2f(x);
#else
    float r; asm("v_exp_f32 %0, %1" : "=v"(r) : "v"(x)); return r;
#endif
}

__device__ __forceinline__ void gload_lds16(const void* g, void* l) {
    __builtin_amdgcn_global_load_lds(
        (const __attribute__((address_space(1))) void*)g,
        (__attribute__((address_space(3))) void*)l, 16, 0, 0);
}

// K=16 bf16 MFMA (v_mfma_f32_16x16x16_bf16: A/B = 4 bf16, C/D = 4 f32).
__device__ __forceinline__ f32x4 mfma16x16x16bf16(v4s a, v4s b, f32x4 c) {
#if __has_builtin(__builtin_amdgcn_mfma_f32_16x16x16bf16_1k)
    return __builtin_amdgcn_mfma_f32_16x16x16bf16_1k(a, b, c, 0, 0, 0);
#else
    f32x4 d;
    asm("v_mfma_f32_16x16x16_bf16 %0, %1, %2, %0"
        : "=v"(d) : "v"(a), "v"(b), "0"(c));
    return d;
#endif
}

// ============================================================================
// Cast fp32 -> bf16.  R9: grid right-sized 20480 -> 5120 blocks (75% of the
// weight-row blocks were no-op launches); x-tensor grid-strides 4 passes.
// ============================================================================
__global__ __launch_bounds__(256) void cast5_kernel(
    const float* __restrict__ x, const float* __restrict__ wq,
    const float* __restrict__ wk, const float* __restrict__ wv,
    const float* __restrict__ wo,
    unsigned short* __restrict__ xo, unsigned short* __restrict__ wqo,
    unsigned short* __restrict__ wko, unsigned short* __restrict__ wvo,
    unsigned short* __restrict__ woo)
{
    const int tid = blockIdx.x * 256 + threadIdx.x;     // 0..262143
    if (blockIdx.y == 0) {
        const int n4 = BB * TT * DD / 4;                // 1,048,576
#pragma unroll
        for (int p = 0; p < 4; ++p) {
            const int i = tid + (p << 18);              // stride 262144
            if (i < n4) {
                float4 v = ((const float4*)x)[i];
                ushort4 o;
                o.x = f2bf(v.x); o.y = f2bf(v.y); o.z = f2bf(v.z); o.w = f2bf(v.w);
                ((ushort4*)xo)[i] = o;
            }
        }
    } else {
        const float* s; unsigned short* d;
        switch (blockIdx.y) {
            case 1: s = wq; d = wqo; break;
            case 2: s = wk; d = wko; break;
            case 3: s = wv; d = wvo; break;
            default: s = wo; d = woo; break;
        }
        // DD*DD/4 = 262144 = exactly one element per thread
        float4 v = ((const float4*)s)[tid];
        ushort4 o;
        o.x = f2bf(v.x); o.y = f2bf(v.y); o.z = f2bf(v.z); o.w = f2bf(v.w);
        ((ushort4*)d)[tid] = o;
    }
}

// ============================================================================
// QKV projection, R9: BK 32 -> 64.  R8 proved conflicts are ~0 and time is
// unchanged -> the cost is the per-iteration barrier (vmcnt drain of loads
// issued ~150cy earlier, L2 latency 200-400cy, ~2.6 blocks/CU).  Halve the
// barrier count (16 iters), double compute per barrier (16 MFMA/wave/iter).
// LDS 48 KB: rows now 64 ushorts = 128 B = bank-aligned.  Swizzle: LDS chunk
// p of row r holds global chunk p^(r&7) (linear DMA dest, pre-swizzled
// source); fragment read at chunk (4h+quad)^(l15&7) -> 8 lanes/slot = b128
// structural floor.  K pre-scaled by 0.125*log2e for base-2 softmax.
// ============================================================================
__global__ __launch_bounds__(256, 3) void qkv_mfma(
    const unsigned short* __restrict__ x,
    const unsigned short* __restrict__ wq, const unsigned short* __restrict__ wk,
    const unsigned short* __restrict__ wv,
    unsigned short* __restrict__ qo, unsigned short* __restrict__ ko,
    unsigned short* __restrict__ vo)
{
    __shared__ unsigned short SMEM[24576];    // 48 KB: A 2x16KB + B 2x8KB

    const int tid = threadIdx.x;
    const int lane = tid & 63;
    const int wid = tid >> 6;
    const int l15 = lane & 15, quad = lane >> 4;
    const int l7 = l15 & 7;

    const int m0 = blockIdx.x << 7;           // 128 m-rows
    const int ny = blockIdx.y;                // 0..47
    const int which = ny >> 4;                // 0=q 1=k 2=v
    const int n0 = (ny & 15) << 6;            // 64 n-rows
    const unsigned short* W = (which == 0) ? wq : (which == 1) ? wk : wv;

    const int wm = (wid >> 1) << 6;           // 0 / 64
    const int wn = (wid & 1) << 5;            // 0 / 32

    char* const smem = (char*)SMEM;

    // staging pass p: byte f = tid*16 + p*4096 in tile; row r = f>>7 (128B
    // rows), LDS chunk ch = (f>>4)&7 holds global chunk ch^(r&7).
#define QKV_STAGE(k0, buf)                                                     \
    do {                                                                       \
        _Pragma("unroll") for (int p = 0; p < 4; ++p) {                        \
            const int f = (tid << 4) + (p << 12);                              \
            const int r = f >> 7;                                              \
            const int gc = ((((f >> 4) & 7) ^ (r & 7)) << 3);                  \
            gload_lds16(&x[(size_t)(m0 + r) * DD + (k0) + gc],                 \
                        smem + (buf) * 16384 + f);                             \
        }                                                                      \
        _Pragma("unroll") for (int p = 0; p < 2; ++p) {                        \
            const int f = (tid << 4) + (p << 12);                              \
            const int r = f >> 7;                                              \
            const int gc = ((((f >> 4) & 7) ^ (r & 7)) << 3);                  \
            gload_lds16(&W[(size_t)(n0 + r) * DD + (k0) + gc],                 \
                        smem + 32768 + (buf) * 8192 + f);                      \
        }                                                                      \
    } while (0)

    f32x4 acc[4][2] = {};

    QKV_STAGE(0, 0);
    __syncthreads();

    int cur = 0;
    for (int k0 = 0; k0 < DD; k0 += 64) {
        if (k0 + 64 < DD) QKV_STAGE(k0 + 64, cur ^ 1);

        const char* Ab = smem + cur * 16384;
        const char* Bb = smem + 32768 + cur * 8192;
#pragma unroll
        for (int h = 0; h < 2; ++h) {
            const int rc = (((h << 2) + quad) ^ l7) << 4;   // swizzled chunk
            v8s af[4], bf[2];
#pragma unroll
            for (int i = 0; i < 4; ++i)
                af[i] = *(const v8s*)(Ab + (wm + (i << 4) + l15) * 128 + rc);
#pragma unroll
            for (int j = 0; j < 2; ++j)
                bf[j] = *(const v8s*)(Bb + (wn + (j << 4) + l15) * 128 + rc);
#pragma unroll
            for (int i = 0; i < 4; ++i)
#pragma unroll
                for (int j = 0; j < 2; ++j)
                    acc[i][j] = __builtin_amdgcn_mfma_f32_16x16x32_bf16(
                        af[i], bf[j], acc[i][j], 0, 0, 0);
        }

        __syncthreads();
        cur ^= 1;
    }
#undef QKV_STAGE

    if (which == 2) {
#pragma unroll
        for (int i = 0; i < 4; ++i)
#pragma unroll
            for (int j = 0; j < 2; ++j) {
                const int n = n0 + wn + (j << 4) + l15;
                const int h = n >> 6, hd = n & 63;
                const int mb = m0 + wm + (i << 4) + (quad << 2);
                const int b = mb >> 11, t = mb & 2047;
                ushort4 pk;
                pk.x = f2bf(acc[i][j][0]); pk.y = f2bf(acc[i][j][1]);
                pk.z = f2bf(acc[i][j][2]); pk.w = f2bf(acc[i][j][3]);
                *(ushort4*)&vo[((((size_t)(b * NH + h) << 6) + hd) << 11) + t] = pk;
            }
    } else {
        unsigned short* outp = (which == 0) ? qo : ko;
        // K pre-scale: 1/sqrt(64) * log2(e) -> softmax in base 2 downstream
        const float sc = (which == 1) ? 0.18033688011112042f : 1.0f;
#pragma unroll
        for (int p = 0; p < 2; ++p) {
            __syncthreads();
            if ((wid >> 1) == p) {
#pragma unroll
                for (int i = 0; i < 4; ++i)
#pragma unroll
                    for (int j = 0; j < 2; ++j)
#pragma unroll
                        for (int r = 0; r < 4; ++r) {
                            const int row = (i << 4) + (quad << 2) + r;
                            SMEM[row * 72 + wn + (j << 4) + l15] = f2bf(acc[i][j][r] * sc);
                        }
            }
            __syncthreads();
            const int rr = tid >> 2;              // 0..63
            const int cg = (tid & 3) << 4;        // 0,16,32,48
            const int m = m0 + (p << 6) + rr;
            const int b = m >> 11, t = m & 2047;
#pragma unroll
            for (int k2 = 0; k2 < 2; ++k2) {
                const int col = cg + (k2 << 3);
                const int n = n0 + col;
                const int h = n >> 6, hd = n & 63;
                const uint4 val = *(const uint4*)&SMEM[rr * 72 + col];
                *(uint4*)&outp[(((size_t)(b * NH + h) * TT + t) << 6) + hd] = val;
            }
        }
    }
}

// ============================================================================
// Flash attention (unchanged from R6/R8): 64-row Q tiles, grid 32x32,
// [64][64] LDS tiles with 16B-chunk row-XOR swizzle, base-2 online softmax.
// ============================================================================
__global__ __launch_bounds__(256) void attn_mfma(
    const unsigned short* __restrict__ q, const unsigned short* __restrict__ k,
    const unsigned short* __restrict__ vt, unsigned short* __restrict__ ctx)
{
    __shared__ unsigned short Qs[64][64];
    __shared__ unsigned short Ks[2][64][64];
    __shared__ unsigned short Vts[2][64][64];

    const int tid = threadIdx.x;
    const int lane = tid & 63;
    const int wid = tid >> 6;
    const int l15 = lane & 15, quad = lane >> 4;
    const int r7 = (l15 & 7) << 3;      // read-side row-XOR term (ushorts)

    const int bh = blockIdx.x;
    const int qt = 31 - (int)blockIdx.y;      // longest blocks dispatch first
    const int q0 = qt << 6;
    const int qrow = q0 + (wid << 4) + l15;   // this lane's q-row

    const unsigned short* qb = q + (size_t)bh * TT * HDD;
    const unsigned short* kb = k + (size_t)bh * TT * HDD;
    const unsigned short* vb = vt + (size_t)bh * HDD * TT;   // (HD, T)
    unsigned short* cb = ctx + (size_t)bh * TT * HDD;

    const int cr = tid >> 3;            // staging row 0..31 (x2 rounds)
    const int cc = (tid & 7) << 3;      // staging col (ushort), 16B chunks
    const int cs = cc ^ ((cr & 7) << 3);  // swizzled store col (row&7 XOR)

    // Q tile + K/V tile 0 -> LDS (swizzled stores)
#pragma unroll
    for (int u = 0; u < 2; ++u) {
        const int r = cr + (u << 5);
        *(uint4*)&Qs[r][cs] = *(const uint4*)&qb[(size_t)(q0 + r) * HDD + cc];
    }
    {
        uint4 k0r = *(const uint4*)&kb[(size_t)cr * HDD + cc];
        uint4 k1r = *(const uint4*)&kb[(size_t)(cr + 32) * HDD + cc];
        uint4 v0r = *(const uint4*)&vb[((size_t)cr << 11) + cc];
        uint4 v1r = *(const uint4*)&vb[((size_t)(cr + 32) << 11) + cc];
        *(uint4*)&Ks[0][cr][cs] = k0r;
        *(uint4*)&Ks[0][cr + 32][cs] = k1r;
        *(uint4*)&Vts[0][cr][cs] = v0r;
        *(uint4*)&Vts[0][cr + 32][cs] = v1r;
    }
    __syncthreads();

    // Q B-frags, wave-resident for the k-loop (swizzled reads)
    v8s qf[2];
#pragma unroll
    for (int c = 0; c < 2; ++c)
        qf[c] = *(const v8s*)&Qs[(wid << 4) + l15]
                               [(((c << 5) + (quad << 3)) ^ r7)];

    float m_i = -INFINITY, l_i = 0.f;
    f32x4 o[4] = {};                    // O^T: d = m*16 + quad*4 + r, col q=l15

    for (int jt = 0; jt <= qt; ++jt) {
        const int cur = jt & 1;

        // issue global loads for tile jt+1 (land during compute below)
        uint4 k0r, k1r, v0r, v1r;
        const bool pre = (jt < qt);
        if (pre) {
            const int kn = (jt + 1) << 6;
            k0r = *(const uint4*)&kb[(size_t)(kn + cr) * HDD + cc];
            k1r = *(const uint4*)&kb[(size_t)(kn + cr + 32) * HDD + cc];
            v0r = *(const uint4*)&vb[((size_t)cr << 11) + kn + cc];
            v1r = *(const uint4*)&vb[((size_t)(cr + 32) << 11) + kn + cc];
        }

        const int k0 = jt << 6;

        // S^T = K . Q^T : St[k = m*16+quad*4+r][q = l15]
        f32x4 s[4] = {};
        const int kc0 = (quad << 3) ^ r7;         // kf0 col
#pragma unroll
        for (int m = 0; m < 4; ++m) {
            const v8s kf0 = *(const v8s*)&Ks[cur][(m << 4) + l15][kc0];
            const v8s kf1 = *(const v8s*)&Ks[cur][(m << 4) + l15][kc0 ^ 32];
            s[m] = __builtin_amdgcn_mfma_f32_16x16x32_bf16(kf0, qf[0], s[m], 0, 0, 0);
            s[m] = __builtin_amdgcn_mfma_f32_16x16x32_bf16(kf1, qf[1], s[m], 0, 0, 0);
        }

        if (jt == qt) {                 // causal mask, diagonal tile only
#pragma unroll
            for (int m = 0; m < 4; ++m) {
                const int kc = k0 + (m << 4) + (quad << 2);
#pragma unroll
                for (int r = 0; r < 4; ++r)
                    if (kc + r > qrow) s[m][r] = -INFINITY;
            }
        }

        // online softmax (base 2): one q-row per lane, 2 shfl for row-max
        float mx = fmaxf(fmaxf(s[0][0], s[0][1]), fmaxf(s[0][2], s[0][3]));
        mx = fmaxf(mx, fmaxf(fmaxf(s[1][0], s[1][1]), fmaxf(s[1][2], s[1][3])));
        mx = fmaxf(mx, fmaxf(fmaxf(s[2][0], s[2][1]), fmaxf(s[2][2], s[2][3])));
        mx = fmaxf(mx, fmaxf(fmaxf(s[3][0], s[3][1]), fmaxf(s[3][2], s[3][3])));
        mx = fmaxf(mx, __shfl_xor(mx, 16));
        mx = fmaxf(mx, __shfl_xor(mx, 32));
        const float m_new = fmaxf(m_i, mx);
        const float alpha = fexp2(m_i - m_new);
        m_i = m_new;

        float sum = 0.f;
        v4s pf[4];
#pragma unroll
        for (int m = 0; m < 4; ++m) {
            const float p0 = fexp2(s[m][0] - m_new);
            const float p1 = fexp2(s[m][1] - m_new);
            const float p2 = fexp2(s[m][2] - m_new);
            const float p3 = fexp2(s[m][3] - m_new);
            sum += (p0 + p1) + (p2 + p3);
            pf[m] = pack_bf16x4(p0, p1, p2, p3);
        }
        sum += __shfl_xor(sum, 16);
        sum += __shfl_xor(sum, 32);
        l_i = l_i * alpha + sum;

#pragma unroll
        for (int m = 0; m < 4; ++m)
#pragma unroll
            for (int r = 0; r < 4; ++r)
                o[m][r] *= alpha;

        // O^T += Vt . P^T  (swizzled b64 reads)
#pragma unroll
        for (int m = 0; m < 4; ++m)
#pragma unroll
            for (int c = 0; c < 4; ++c) {
                const v4s vf = *(const v4s*)&Vts[cur][(m << 4) + l15]
                                                    [(((c << 4) + (quad << 2)) ^ r7)];
                o[m] = mfma16x16x16bf16(vf, pf[c], o[m]);
            }

        // publish tile jt+1 into the other buffer (swizzled stores)
        if (pre) {
            const int nxt = cur ^ 1;
            *(uint4*)&Ks[nxt][cr][cs] = k0r;
            *(uint4*)&Ks[nxt][cr + 32][cs] = k1r;
            *(uint4*)&Vts[nxt][cr][cs] = v0r;
            *(uint4*)&Vts[nxt][cr + 32][cs] = v1r;
        }
        __syncthreads();
    }

    // normalize + store: ctx[q][d], d = m*16 + quad*4 + r (8B stores)
    const float linv = 1.f / l_i;
#pragma unroll
    for (int m = 0; m < 4; ++m) {
        ushort4 st;
        st.x = f2bf(o[m][0] * linv); st.y = f2bf(o[m][1] * linv);
        st.z = f2bf(o[m][2] * linv); st.w = f2bf(o[m][3] * linv);
        *(ushort4*)&cb[((size_t)qrow << 6) + (m << 4) + (quad << 2)] = st;
    }
}

// ============================================================================
// Output projection, R9: same BK=64 transformation as qkv (16 barriers
// instead of 32; 2 blocks/CU is all the TLP available, so per-barrier
// amortization matters most here).  128x64 tiles, grid (32,16).
// ============================================================================
__global__ __launch_bounds__(256, 3) void oproj_mfma(
    const unsigned short* __restrict__ c, const unsigned short* __restrict__ wo,
    const float* __restrict__ bo, float* __restrict__ out)
{
    __shared__ unsigned short SMEM[24576];    // 48 KB: A 2x16KB + B 2x8KB

    const int tid = threadIdx.x;
    const int lane = tid & 63;
    const int wid = tid >> 6;
    const int l15 = lane & 15, quad = lane >> 4;
    const int l7 = l15 & 7;

    const int m0 = blockIdx.x << 7;           // 128 m-rows
    const int n0 = blockIdx.y << 6;           // 64 n-rows
    const int wm = (wid >> 1) << 6;           // 0 / 64
    const int wn = (wid & 1) << 5;            // 0 / 32

    char* const smem = (char*)SMEM;

#define OP_STAGE(k0, buf)                                                      \
    do {                                                                       \
        _Pragma("unroll") for (int p = 0; p < 4; ++p) {                        \
            const int f = (tid << 4) + (p << 12);                              \
            const int r = f >> 7;                                              \
            const int gc = ((((f >> 4) & 7) ^ (r & 7)) << 3);                  \
            gload_lds16(&c[(size_t)(m0 + r) * DD + (k0) + gc],                 \
                        smem + (buf) * 16384 + f);                             \
        }                                                                      \
        _Pragma("unroll") for (int p = 0; p < 2; ++p) {                        \
            const int f = (tid << 4) + (p << 12);                              \
            const int r = f >> 7;                                              \
            const int gc = ((((f >> 4) & 7) ^ (r & 7)) << 3);                  \
            gload_lds16(&wo[(size_t)(n0 + r) * DD + (k0) + gc],                \
                        smem + 32768 + (buf) * 8192 + f);                      \
        }                                                                      \
    } while (0)

    f32x4 acc[4][2] = {};

    OP_STAGE(0, 0);
    __syncthreads();

    int cur = 0;
    for (int k0 = 0; k0 < DD; k0 += 64) {
        if (k0 + 64 < DD) OP_STAGE(k0 + 64, cur ^ 1);

        const char* Ab = smem + cur * 16384;
        const char* Bb = smem + 32768 + cur * 8192;
#pragma unroll
        for (int h = 0; h < 2; ++h) {
            const int rc = (((h << 2) + quad) ^ l7) << 4;
            v8s af[4], bf[2];
#pragma unroll
            for (int i = 0; i < 4; ++i)
                af[i] = *(const v8s*)(Ab + (wm + (i << 4) + l15) * 128 + rc);
#pragma unroll
            for (int j = 0; j < 2; ++j)
                bf[j] = *(const v8s*)(Bb + (wn + (j << 4) + l15) * 128 + rc);
#pragma unroll
            for (int i = 0; i < 4; ++i)
#pragma unroll
                for (int j = 0; j < 2; ++j)
                    acc[i][j] = __builtin_amdgcn_mfma_f32_16x16x32_bf16(
                        af[i], bf[j], acc[i][j], 0, 0, 0);
        }

        __syncthreads();
        cur ^= 1;
    }
#undef OP_STAGE

#pragma unroll
    for (int j = 0; j < 2; ++j) {
        const int n = n0 + wn + (j << 4) + l15;
        const float bias = bo[n];
#pragma unroll
        for (int i = 0; i < 4; ++i) {
            const int mb = m0 + wm + (i << 4) + (quad << 2);
#pragma unroll
            for (int r = 0; r < 4; ++r)
                out[(size_t)(mb + r) * DD + n] = acc[i][j][r] + bias;
        }
    }
}

extern "C" void kernel_launch(void* const* d_in, const int* in_sizes, int n_in,
                              void* d_out, int out_size, void* d_ws, size_t ws_size,
                              hipStream_t stream) {
    const float* x  = (const float*)d_in[0];
    const float* Wq = (const float*)d_in[1];
    const float* Wk = (const float*)d_in[2];
    const float* Wv = (const float*)d_in[3];
    const float* Wo = (const float*)d_in[4];
    const float* bo = (const float*)d_in[5];
    float* out = (float*)d_out;

    const size_t NX = (size_t)BB * TT * DD;
    const size_t NW = (size_t)DD * DD;

    unsigned short* xb  = (unsigned short*)d_ws;
    unsigned short* wqb = xb + NX;
    unsigned short* wkb = wqb + NW;
    unsigned short* wvb = wkb + NW;
    unsigned short* wob = wvb + NW;
    unsigned short* qb  = wob + NW;
    unsigned short* kb  = qb + NX;
    unsigned short* vtb = kb + NX;
    unsigned short* cbuf = vtb + NX;

    cast5_kernel<<<dim3(1024, 5), 256, 0, stream>>>(x, Wq, Wk, Wv, Wo,
                                                    xb, wqb, wkb, wvb, wob);
    qkv_mfma<<<dim3(32, 48), 256, 0, stream>>>(xb, wqb, wkb, wvb, qb, kb, vtb);
    attn_mfma<<<dim3(32, 32), 256, 0, stream>>>(qb, kb, vtb, cbuf);
    oproj_mfma<<<dim3(32, 16), 256, 0, stream>>>(cbuf, wob, bo, out);
}